// Round 6
// baseline (112.030 us; speedup 1.0000x reference)
//
#include <hip/hip_runtime.h>

// Problem constants
#define Tin 12     // T_IN
#define Ttot 24    // T_TOTAL
#define NN 5000    // nodes
#define KK 16      // neighbors
#define HH 4       // heads
#define OO 12      // T_TOTAL - T_IN
#define TH 48      // Tin * HH
#define G  8       // bt-groups (2 batches each) == number of XCDs
#define JJ 24      // (b,t) pairs per group

// Native clang vectors (HIP float4 is a class the builtins reject).
typedef float nfloat4 __attribute__((ext_vector_type(4)));
typedef float f2 __attribute__((ext_vector_type(2)));   // packed-f32 pairs

__device__ __forceinline__ float4 nt_load4(const float4* p) {
    nfloat4 v = __builtin_nontemporal_load((const nfloat4*)p);
    return *(float4*)&v;
}
__device__ __forceinline__ void nt_store4(float4 v, float4* p) {
    __builtin_nontemporal_store(*(nfloat4*)&v, (nfloat4*)p);
}

// ======= kernel 1: x (BT,N) f4 rows -> xT3[g][n][c][b_l][t] f32 + concat ====
// New layout: per (g,node) a 384 B row ordered (c:4, b_l:2, t:12) so one
// k2-thread (n,b_l,c) reads its 48 B t-slice with 3 x b128.
#define K1_NB 64
#define K1_BT 24

__global__ __launch_bounds__(256) void transpose_concat_kernel(
    const float4* __restrict__ x4,   // (BT, N)
    float* __restrict__ xT3,         // (G, N, 4, 2, 12) floats
    float4* __restrict__ out4)       // (B*Ttot, N)
{
    __shared__ float4 tile[K1_BT][K1_NB + 1];
    const int n0  = blockIdx.x * K1_NB;
    const int g   = blockIdx.y;
    const int bt0 = g * K1_BT;
    const int rem = min(K1_NB, NN - n0);
    const int tid = threadIdx.x;

    #pragma unroll
    for (int r = 0; r < (K1_NB * K1_BT) / 256; r++) {
        int tau = r * 256 + tid;
        int j = tau / K1_NB;
        int i = tau % K1_NB;
        if (i < rem) {
            int bt = bt0 + j;
            float4 v = nt_load4(&x4[(size_t)bt * NN + n0 + i]);
            tile[j][i] = v;
            int b = bt / Tin, t = bt - b * Tin;
            nt_store4(v, &out4[(size_t)(b * Ttot + t) * NN + n0 + i]);
        }
    }
    __syncthreads();

    // write xT3: 24 f4 units per node; unit remu = c*6 + b_l*3 + tq,
    // unit value = x[2g+b_l][4tq..4tq+3][n][c]  (contiguous 384 B per node)
    float4* xT3g4 = (float4*)(xT3 + (size_t)g * NN * 96);
    #pragma unroll
    for (int r = 0; r < 6; r++) {
        int u = r * 256 + tid;
        int i = u / 24;
        int remu = u - i * 24;
        if (i < rem) {
            int c  = remu / 6;
            int s  = remu - c * 6;
            int bl = s / 3;
            int tq = s - bl * 3;
            int j0 = bl * 12 + tq * 4;
            float4 o;
            o.x = ((const float*)&tile[j0 + 0][i])[c];
            o.y = ((const float*)&tile[j0 + 1][i])[c];
            o.z = ((const float*)&tile[j0 + 2][i])[c];
            o.w = ((const float*)&tile[j0 + 3][i])[c];
            xT3g4[(size_t)(n0 + i) * 24 + remu] = o;
        }
    }
}

// ======= kernel 2: register-resident gather+aggregate+GEMM =================
// Thread = (node nl, b_l, c). feat[4h][6 t-pairs] lives in 48 VGPRs.
// No feat LDS, no inter-phase barrier. 1000 blocks (125/group x 8 XCD-pinned),
// 320 threads (40 nodes x 8).
#define NPB 40
#define NTH 320

__global__ __launch_bounds__(NTH) void gnn_main_kernel(
    const float* __restrict__ xT3,   // (G, N, 4, 2, 12) f32
    const float* __restrict__ dists, // (N, K)
    const float* __restrict__ W,     // (48, 12)
    const float* __restrict__ bias,  // (12,)
    const int*   __restrict__ nbrs,  // (N, K)
    float* __restrict__ outf)        // (B*Ttot, N, 4) floats
{
    __shared__ float4 w4_s[NPB][KK + 1];        // +1 f4 pad: nl spread over banks
    __shared__ int    nbroff_s[NPB][KK + 1];    // +1 int pad: byte offsets nbr*384
    __shared__ __align__(16) float Wt_s[OO * TH];  // Wt[o][h][t] = W[(t*4+h)*12+o]
    __shared__ float  bias_s[OO];

    const int bid = blockIdx.x;
    const int g   = bid & 7;                    // XCD pin (locality only)
    const int n0  = (bid >> 3) * NPB;
    const int tid = threadIdx.x;

    // ---- stage: transposed W, bias, gaussian head-weights, nbr offsets ----
    for (int i = tid; i < OO * TH; i += NTH) {
        int o = i / TH;
        int r = i - o * TH;                     // h*12 + t
        int h = r / Tin;
        int t = r - h * Tin;
        Wt_s[i] = W[(t * HH + h) * OO + o];
    }
    if (tid < OO) bias_s[tid] = bias[tid];
    #pragma unroll
    for (int r = 0; r < 2; r++) {               // 640 = 2*320 items exact
        int u = r * NTH + tid;
        int nl = u >> 4, k = u & 15;
        nbroff_s[nl][k] = nbrs[(n0 + nl) * KK + k] * 384;
        float d = dists[(n0 + nl) * KK + k];
        float p = expf(-(d * d) * (1.0f / 144.0f));  // head h uses p^(h+1)
        float4 wv;
        wv.x = p; wv.y = p * p; wv.z = wv.y * p; wv.w = wv.y * wv.y;
        w4_s[nl][k] = wv;
    }
    __syncthreads();

    // ---- thread identity ----
    const int nl  = tid >> 3;            // 0..39
    const int rr  = tid & 7;
    const int c   = rr & 3;              // lane-fastest -> coalesced stores
    const int b_l = rr >> 2;
    const char* xgb = (const char*)xT3 + (size_t)g * (NN * 96 * 4);
    const unsigned sl = (unsigned)(c * 2 + b_l) * 48u;   // byte offset in row

    // ---- gather + aggregate, fully in registers ----
    f2 fp[HH][6];                        // feat[h][t-pair], 48 VGPRs
    #pragma unroll
    for (int h = 0; h < HH; h++)
        #pragma unroll
        for (int tp = 0; tp < 6; tp++) fp[h][tp] = f2{0.f, 0.f};

    #pragma unroll
    for (int k = 0; k < KK; k++) {
        unsigned off = (unsigned)nbroff_s[nl][k] + sl;
        const nfloat4* px = (const nfloat4*)(xgb + off);
        nfloat4 x0 = px[0], x1 = px[1], x2 = px[2];   // 12 t-values
        float4 wv = w4_s[nl][k];                       // broadcast, conflict-free
        f2 xp[6] = { f2{x0.x, x0.y}, f2{x0.z, x0.w},
                     f2{x1.x, x1.y}, f2{x1.z, x1.w},
                     f2{x2.x, x2.y}, f2{x2.z, x2.w} };
        f2 wp[HH] = { f2{wv.x, wv.x}, f2{wv.y, wv.y},
                      f2{wv.z, wv.z}, f2{wv.w, wv.w} };
        #pragma unroll
        for (int h = 0; h < HH; h++)
            #pragma unroll
            for (int tp = 0; tp < 6; tp++)
                fp[h][tp] += wp[h] * xp[tp];           // pk-f32 pairs
    }

    // ---- (48 -> 12) GEMM from registers; Wt_s reads are uniform broadcasts --
    const int b = g * 2 + b_l;
    const size_t outbase = ((size_t)(b * Ttot + Tin) * NN + (n0 + nl)) * 4 + c;
    #pragma unroll
    for (int o = 0; o < OO; o++) {
        f2 acc = f2{0.f, 0.f};
        #pragma unroll
        for (int h = 0; h < HH; h++) {
            #pragma unroll
            for (int qq = 0; qq < 3; qq++) {
                nfloat4 wq = *(const nfloat4*)&Wt_s[o * TH + h * Tin + qq * 4];
                acc += f2{wq.x, wq.y} * fp[h][2 * qq];
                acc += f2{wq.z, wq.w} * fp[h][2 * qq + 1];
            }
        }
        float y = acc.x + acc.y + bias_s[o];
        y = fmaxf(y, 0.f);
        outf[outbase + (size_t)o * (NN * 4)] = y;
    }
}

extern "C" void kernel_launch(void* const* d_in, const int* in_sizes, int n_in,
                              void* d_out, int out_size, void* d_ws, size_t ws_size,
                              hipStream_t stream) {
    const float* x     = (const float*)d_in[0];
    const float* dists = (const float*)d_in[1];
    const float* W     = (const float*)d_in[2];
    const float* bias  = (const float*)d_in[3];
    const int*   nbrs  = (const int*)d_in[4];
    float4* out4 = (float4*)d_out;
    float*  xT3  = (float*)d_ws;      // G*NN*96*4 B = 15.36 MB of ws

    dim3 g1((NN + K1_NB - 1) / K1_NB, G);          // (79, 8)
    hipLaunchKernelGGL(transpose_concat_kernel, g1, dim3(256), 0, stream,
                       (const float4*)x, xT3, out4);

    hipLaunchKernelGGL(gnn_main_kernel, dim3((NN / NPB) * G), dim3(NTH), 0, stream,
                       xT3, dists, W, bias, nbrs, (float*)d_out);
}

// Round 7
// 109.001 us; speedup vs baseline: 1.0278x; 1.0278x over previous
//
#include <hip/hip_runtime.h>

// Problem constants
#define Bz 16      // batch
#define Tin 12     // T_IN
#define Ttot 24    // T_TOTAL
#define NN 5000    // nodes
#define KK 16      // neighbors
#define HH 4       // heads
#define OO 12      // T_TOTAL - T_IN
#define TH 48      // Tin * HH
#define G  8       // bt-groups (2 batches each) == number of XCDs
#define JJ 24      // (b,t) pairs per group

// Native clang vectors (HIP float4 is a class type the builtins reject).
typedef float nfloat4 __attribute__((ext_vector_type(4)));
typedef float f2 __attribute__((ext_vector_type(2)));   // packed-math pairs

__device__ __forceinline__ float4 nt_load4(const float4* p) {
    nfloat4 v = __builtin_nontemporal_load((const nfloat4*)p);
    return *(float4*)&v;
}
__device__ __forceinline__ void nt_store4(float4 v, float4* p) {
    __builtin_nontemporal_store(*(nfloat4*)&v, (nfloat4*)p);
}

// ============ kernel 1: transpose x -> xT2(g, N, 24) + concat copy ==========
// 1D grid, g = bid % 8: SAME XCD-assignment scheme as kernel 2, so the XCD
// that WRITES xT2 slice g is the XCD that READS it (L2 write-allocate ->
// k2's gather becomes an L2-local hit instead of a cross-die cold miss).
#define K1_NB 64   // nodes per tile
#define K1_BT 24   // (b,t) pairs per tile == JJ
#define K1_TILES 79   // ceil(5000/64)

__global__ __launch_bounds__(256) void transpose_concat_kernel(
    const float4* __restrict__ x4,   // (BT, N)
    float4* __restrict__ xT2,        // (G, N, JJ)
    float4* __restrict__ out4)       // (B*Ttot, N)
{
    __shared__ float4 tile[K1_BT][K1_NB + 1];
    const int bid = blockIdx.x;
    const int g   = bid & 7;              // XCD pin == producer of slice g
    const int n0  = (bid >> 3) * K1_NB;
    const int bt0 = g * K1_BT;
    const int rem = min(K1_NB, NN - n0);
    const int tid = threadIdx.x;

    #pragma unroll
    for (int r = 0; r < (K1_NB * K1_BT) / 256; r++) {
        int tau = r * 256 + tid;
        int j = tau / K1_NB;
        int i = tau % K1_NB;
        if (i < rem) {
            int bt = bt0 + j;
            float4 v = nt_load4(&x4[(size_t)bt * NN + n0 + i]);
            tile[j][i] = v;
            int b = bt / Tin, t = bt - b * Tin;
            nt_store4(v, &out4[(size_t)(b * Ttot + t) * NN + n0 + i]);
        }
    }
    __syncthreads();

    // xT2 IS re-read by kernel 2 on THIS XCD -> regular (allocating) store.
    #pragma unroll
    for (int r = 0; r < (K1_NB * K1_BT) / 256; r++) {
        int tau = r * 256 + tid;
        int i = tau / K1_BT;
        int j = tau - i * K1_BT;
        if (i < rem) {
            xT2[((size_t)g * NN + (n0 + i)) * JJ + j] = tile[j][i];
        }
    }
}

// ============ kernel 2: per-(g, node-block) gather + aggregate + GEMM =======
// grid.x = 625*8; g = blockIdx.x % 8 -> XCD-pinned; slice g is L2-resident
// on XCD g thanks to kernel 1's matching pinning.
#define NPB 8                  // nodes per block
// Compact feat layout (float4 units): L = nl*FSN2 + b_l*FSB2 + h*12 + t
#define FSB2 49
#define FSN2 99                // 2*49 + 1
#define WTS  52                // Wt_s row stride in floats

__global__ __launch_bounds__(192) void gnn_main_kernel(
    const float4* __restrict__ xT2,   // (G, N, JJ)
    const float* __restrict__ dists,  // (N, K)
    const float* __restrict__ W,      // (48, 12)
    const float* __restrict__ bias,   // (12,)
    const int*   __restrict__ nbrs,   // (N, K)
    float4* __restrict__ out4)        // (B*Ttot, N)
{
    __shared__ float4 feat[NPB * FSN2];     // 12.4 KB
    __shared__ float4 w4_s[NPB][KK + 1];    // +1 f4 pad: kills 3-way read conflict
    __shared__ float  Wt_s[OO * WTS];       // W transposed: Wt[o][t*4+h], padded
    __shared__ float  bias_s[OO];
    __shared__ int    nbroff_s[NPB][KK + 1];// pre-scaled BYTE offsets: nbr*384

    const int bid = blockIdx.x;
    const int g   = bid & 7;
    const int n0  = (bid >> 3) * NPB;
    const int tid = threadIdx.x;

    // ---- stage small tensors ----
    for (int i = tid; i < OO * WTS; i += 192) {
        int o = i / WTS, col = i - o * WTS;
        if (col < TH) Wt_s[i] = W[col * OO + o];
    }
    if (tid < OO) bias_s[tid] = bias[tid];
    if (tid < NPB * KK) {
        int nl = tid >> 4, k = tid & 15;
        nbroff_s[nl][k] = nbrs[(n0 + nl) * KK + k] * (JJ * (int)sizeof(float4));
        float d = dists[(n0 + nl) * KK + k];
        float p = expf(-(d * d) * (1.0f / 144.0f));   // head h uses p^(h+1)
        float4 wv;
        wv.x = p;
        wv.y = p * p;
        wv.z = wv.y * p;
        wv.w = wv.y * wv.y;
        w4_s[nl][k] = wv;
    }
    __syncthreads();

    // ---- phase A: gather (384 B contiguous rows) + head-weighted aggregate --
    {
        const int nl  = tid / JJ;            // 0..7
        const int j   = tid - nl * JJ;       // 0..23
        const int b_l = j / Tin;             // 0..1
        const int t   = j - b_l * Tin;       // 0..11
        const char* xgb = (const char*)xT2 + (size_t)g * (NN * JJ * sizeof(float4));
        const unsigned j16 = (unsigned)j * 16u;

        f2 a0l = {0,0}, a0h = {0,0}, a1l = {0,0}, a1h = {0,0};
        f2 a2l = {0,0}, a2h = {0,0}, a3l = {0,0}, a3h = {0,0};
        #pragma unroll
        for (int k = 0; k < KK; k++) {
            unsigned off = (unsigned)nbroff_s[nl][k] + j16;
            float4 xv = *(const float4*)(xgb + off);
            f2 xl = {xv.x, xv.y}, xh = {xv.z, xv.w};
            float4 wv = w4_s[nl][k];
            f2 w0 = {wv.x, wv.x}, w1 = {wv.y, wv.y};
            f2 w2 = {wv.z, wv.z}, w3 = {wv.w, wv.w};
            a0l += w0 * xl; a0h += w0 * xh;
            a1l += w1 * xl; a1h += w1 * xh;
            a2l += w2 * xl; a2h += w2 * xh;
            a3l += w3 * xl; a3h += w3 * xh;
        }
        const int base = nl * FSN2 + b_l * FSB2 + t;    // + h*12
        feat[base +  0] = float4{a0l.x, a0l.y, a0h.x, a0h.y};
        feat[base + 12] = float4{a1l.x, a1l.y, a1h.x, a1h.y};
        feat[base + 24] = float4{a2l.x, a2l.y, a2h.x, a2h.y};
        feat[base + 36] = float4{a3l.x, a3l.y, a3h.x, a3h.y};
    }
    __syncthreads();

    // ---- phase B: (48 -> 12) GEMM, 1 wave, 3 outputs/thread ----
    if (tid < 64) {
        const int nl   = tid & 7;            // 0..7
        const int rest = tid >> 3;           // 0..7
        const int b_l  = rest & 1;           // 0..1
        const int o3   = rest >> 1;          // 0..3 -> o = 3*o3 + {0,1,2}
        const int o0   = 3 * o3;

        float4 acc[3];
        #pragma unroll
        for (int i = 0; i < 3; i++) {
            float bz = bias_s[o0 + i];
            acc[i] = float4{bz, bz, bz, bz};
        }
        const int fb = nl * FSN2 + b_l * FSB2;
        #pragma unroll
        for (int t = 0; t < Tin; t++) {
            float4 f0 = feat[fb + t];            // h=0
            float4 f1 = feat[fb + 12 + t];       // h=1
            float4 fq = feat[fb + 24 + t];       // h=2
            float4 f3 = feat[fb + 36 + t];       // h=3
            f2 f0l = {f0.x, f0.y}, f0h = {f0.z, f0.w};
            f2 f1l = {f1.x, f1.y}, f1h = {f1.z, f1.w};
            f2 f2l = {fq.x, fq.y}, f2h = {fq.z, fq.w};
            f2 f3l = {f3.x, f3.y}, f3h = {f3.z, f3.w};
            #pragma unroll
            for (int i = 0; i < 3; i++) {
                const float4 wq = *(const float4*)&Wt_s[(o0 + i) * WTS + t * 4];
                f2 al = {acc[i].x, acc[i].y}, ah = {acc[i].z, acc[i].w};
                f2 wx = {wq.x, wq.x}, wy = {wq.y, wq.y};
                f2 wz = {wq.z, wq.z}, ww = {wq.w, wq.w};
                al += wx * f0l; ah += wx * f0h;
                al += wy * f1l; ah += wy * f1h;
                al += wz * f2l; ah += wz * f2h;
                al += ww * f3l; ah += ww * f3h;
                acc[i] = float4{al.x, al.y, ah.x, ah.y};
            }
        }
        const int b = g * 2 + b_l;
        #pragma unroll
        for (int i = 0; i < 3; i++) {
            int o = o0 + i;
            float4 y = acc[i];
            y.x = fmaxf(y.x, 0.0f); y.y = fmaxf(y.y, 0.0f);
            y.z = fmaxf(y.z, 0.0f); y.w = fmaxf(y.w, 0.0f);
            nt_store4(y, &out4[(size_t)(b * Ttot + Tin + o) * NN + n0 + nl]);
        }
    }
}

extern "C" void kernel_launch(void* const* d_in, const int* in_sizes, int n_in,
                              void* d_out, int out_size, void* d_ws, size_t ws_size,
                              hipStream_t stream) {
    const float* x     = (const float*)d_in[0];
    const float* dists = (const float*)d_in[1];
    const float* W     = (const float*)d_in[2];
    const float* bias  = (const float*)d_in[3];
    const int*   nbrs  = (const int*)d_in[4];
    float4* out4 = (float4*)d_out;
    float4* xT2  = (float4*)d_ws;     // G*NN*JJ*16 B = 15.36 MB of ws

    // k1: 1D grid, 632 = 79 tiles x 8 groups; g = bid % 8 (XCD-matched to k2)
    hipLaunchKernelGGL(transpose_concat_kernel, dim3(K1_TILES * G), dim3(256), 0,
                       stream, (const float4*)x, xT2, out4);

    hipLaunchKernelGGL(gnn_main_kernel, dim3((NN / NPB) * G), dim3(192), 0, stream,
                       (const float4*)xT2, dists, W, bias, nbrs, out4);
}